// Round 20
// baseline (629.121 us; speedup 1.0000x reference)
//
#include <hip/hip_runtime.h>
#include <hip/hip_bf16.h>

#define NN 16000
#define CC 128
#define EE 256000
#define AA 10

typedef short short8_t __attribute__((ext_vector_type(8)));
typedef float f32x4 __attribute__((ext_vector_type(4)));
typedef unsigned short u16x4 __attribute__((ext_vector_type(4)));

__device__ __forceinline__ float silu_f(float x) {
    return x / (1.0f + __expf(-x));
}

__device__ __forceinline__ float bf2f(unsigned short u) {
    unsigned int x = ((unsigned int)u) << 16;
    float f;
    __builtin_memcpy(&f, &x, 4);
    return f;
}

__device__ __forceinline__ unsigned short f2bf(float f) {
    __hip_bfloat16 b = __float2bfloat16(f);
    unsigned short u;
    __builtin_memcpy(&u, &b, 2);
    return u;
}

// ---------------- K1: h0/h1 pre-linears -> hb (N,128) ushort4 bf16 [h0, h1x, h1y, h1z]
__global__ __launch_bounds__(256) void pre_kernel(const float* __restrict__ nf,
                                                  const float* __restrict__ Wpre0,
                                                  const float* __restrict__ Wpre1,
                                                  ushort4* __restrict__ hb) {
    __shared__ float4 lx[2][CC];
    const int c = threadIdx.x & 127;
    const int sub = threadIdx.x >> 7;
    const float inv_c = 0.08838834764831843f;
    const int n = blockIdx.x * 2 + sub;
    const float* row = nf + (size_t)n * 512;
    lx[sub][c] = make_float4(row[c], row[128 + 3 * c], row[128 + 3 * c + 1], row[128 + 3 * c + 2]);
    __syncthreads();
    float4 acc = make_float4(0.f, 0.f, 0.f, 0.f);
    #pragma unroll 8
    for (int u = 0; u < 128; ++u) {
        const float w0 = Wpre0[u * 128 + c];
        const float w1 = Wpre1[u * 128 + c];
        const float4 xv = lx[sub][u];
        acc.x += w0 * xv.x;
        acc.y += w1 * xv.y;
        acc.z += w1 * xv.z;
        acc.w += w1 * xv.w;
    }
    ushort4 o;
    o.x = f2bf(acc.x * inv_c);
    o.y = f2bf(acc.y * inv_c);
    o.z = f2bf(acc.z * inv_c);
    o.w = f2bf(acc.w * inv_c);
    hb[(size_t)n * 128 + c] = o;
}

// ---------------- CSR build: count -> scan -> fill perm+ipos (edges sorted by receiver)
__global__ __launch_bounds__(256) void count_kernel(const int* __restrict__ ei,
                                                    int* __restrict__ cnt) {
    const int e = blockIdx.x * 256 + threadIdx.x;
    if (e < EE) atomicAdd(&cnt[ei[EE + e]], 1);
}

__global__ __launch_bounds__(1024) void scan_kernel(const int* __restrict__ cnt,
                                                    int* __restrict__ cur) {
    __shared__ int part[1024];
    const int t = threadIdx.x;
    const int base = t * 16;
    int local[16];
    int s = 0;
    #pragma unroll
    for (int i = 0; i < 16; ++i) {
        const int idx = base + i;
        const int v = (idx < NN) ? cnt[idx] : 0;
        local[i] = s;
        s += v;
    }
    part[t] = s;
    __syncthreads();
    for (int off = 1; off < 1024; off <<= 1) {
        int v = (t >= off) ? part[t - off] : 0;
        __syncthreads();
        part[t] += v;
        __syncthreads();
    }
    const int pre = (t == 0) ? 0 : part[t - 1];
    #pragma unroll
    for (int i = 0; i < 16; ++i) {
        const int idx = base + i;
        if (idx < NN) cur[idx] = pre + local[i];
    }
}

__global__ __launch_bounds__(256) void fill_kernel(const int* __restrict__ ei,
                                                   int* __restrict__ cur,
                                                   int* __restrict__ perm,
                                                   int* __restrict__ ipos) {
    const int e = blockIdx.x * 256 + threadIdx.x;
    if (e < EE) {
        const int r = ei[EE + e];
        const int pos = atomicAdd(&cur[r], 1);
        perm[pos] = e;
        ipos[e] = pos;
    }
}

// ---------------- gather edge metadata into sorted order
__global__ __launch_bounds__(256) void gather_kernel(const int* __restrict__ perm,
                                                     const int* __restrict__ ei,
                                                     const float4* __restrict__ sph4,
                                                     int* __restrict__ ss,
                                                     int* __restrict__ rs,
                                                     float4* __restrict__ Ys) {
    const int e = blockIdx.x * 256 + threadIdx.x;
    const int p = perm[e];
    ss[e] = ei[p];
    rs[e] = ei[EE + p];
    Ys[e] = sph4[p];
}

// ---------------- K2: radial MLP in ORIGINAL order (coalesced rb) -> scatter full
// 128B bf16 rows to hmS[ipos[e]] (full-line writes: no RMW, no fetch amplification).
__global__ __launch_bounds__(256) void mlp_kernel(const float* __restrict__ rb,
                                                  const float* __restrict__ Wm1,
                                                  const float* __restrict__ Wm2,
                                                  const int* __restrict__ ipos,
                                                  unsigned short* __restrict__ hmS) {
    __shared__ float4 sW1[8][16];
    __shared__ float4 sW2[64][16];
    const int tid = threadIdx.x;
    for (int i = tid; i < 8 * 16; i += 256) ((float4*)sW1)[i] = ((const float4*)Wm1)[i];
    for (int i = tid; i < 64 * 16; i += 256) ((float4*)sW2)[i] = ((const float4*)Wm2)[i];
    __syncthreads();
    const int e = blockIdx.x * 256 + tid;
    const float4* rb4 = (const float4*)(rb + (size_t)e * 8);
    const float4 r0 = rb4[0], r1 = rb4[1];
    float r[8] = {r0.x, r0.y, r0.z, r0.w, r1.x, r1.y, r1.z, r1.w};
    float h1[64];
    #pragma unroll
    for (int o4 = 0; o4 < 16; ++o4) {
        float4 a = make_float4(0.f, 0.f, 0.f, 0.f);
        #pragma unroll
        for (int k = 0; k < 8; ++k) {
            const float4 wv = sW1[k][o4];
            a.x += r[k] * wv.x; a.y += r[k] * wv.y; a.z += r[k] * wv.z; a.w += r[k] * wv.w;
        }
        h1[o4 * 4 + 0] = silu_f(a.x);
        h1[o4 * 4 + 1] = silu_f(a.y);
        h1[o4 * 4 + 2] = silu_f(a.z);
        h1[o4 * 4 + 3] = silu_f(a.w);
    }
    union { unsigned short s[64]; uint4 q[8]; } buf;
    #pragma unroll
    for (int o4 = 0; o4 < 16; ++o4) {
        float4 a = make_float4(0.f, 0.f, 0.f, 0.f);
        #pragma unroll 8
        for (int k = 0; k < 64; ++k) {
            const float4 wv = sW2[k][o4];
            a.x += h1[k] * wv.x; a.y += h1[k] * wv.y; a.z += h1[k] * wv.z; a.w += h1[k] * wv.w;
        }
        buf.s[o4 * 4 + 0] = f2bf(silu_f(a.x));
        buf.s[o4 * 4 + 1] = f2bf(silu_f(a.y));
        buf.s[o4 * 4 + 2] = f2bf(silu_f(a.z));
        buf.s[o4 * 4 + 3] = f2bf(silu_f(a.w));
    }
    uint4* dst = (uint4*)(hmS + (size_t)ipos[e] * 64);
    #pragma unroll
    for (int j = 0; j < 8; ++j) dst[j] = buf.q[j];
}

// ---------------- prep: split-bf16 W3T: hi = bf16(W), lo = bf16(W - hi); layout [col][k]
__global__ __launch_bounds__(256) void w3t_kernel(const float* __restrict__ Wm3,
                                                  unsigned short* __restrict__ W3Thi,
                                                  unsigned short* __restrict__ W3Tlo) {
    const int idx = blockIdx.x * 256 + threadIdx.x;  // 0..32767
    const int col = idx >> 6, k = idx & 63;
    const float v = Wm3[k * 512 + col];
    const unsigned short hi = f2bf(v);
    W3Thi[idx] = hi;
    W3Tlo[idx] = f2bf(v - bf2f(hi));
}

// ---------------- K3 (MFMA): w-GEMM over sorted edges + fused messages, run-compressed
// atomics (R17-proven structure, UNMODIFIED).
__global__ __launch_bounds__(512) void wmsgm_kernel(const unsigned short* __restrict__ hmS,
                                                    const unsigned short* __restrict__ W3Thi,
                                                    const unsigned short* __restrict__ W3Tlo,
                                                    const int* __restrict__ ss,
                                                    const int* __restrict__ rs,
                                                    const float4* __restrict__ Ys,
                                                    const ushort4* __restrict__ hb,
                                                    float* __restrict__ Acat) {
    __shared__ int lss[64];
    __shared__ int lrs[64];
    __shared__ float4 lY[64];
    const int tid = threadIdx.x;
    const int ebase = blockIdx.x * 64;
    if (tid < 64) {
        lss[tid] = ss[ebase + tid];
        lrs[tid] = rs[ebase + tid];
        lY[tid] = Ys[ebase + tid];
    }
    const int w = tid >> 6, lane = tid & 63;
    const int l15 = lane & 15, lk = lane >> 4;

    f32x4 acc[4][4];
    #pragma unroll
    for (int mf = 0; mf < 4; ++mf)
        #pragma unroll
        for (int g = 0; g < 4; ++g) acc[mf][g] = (f32x4){0.f, 0.f, 0.f, 0.f};

    // two passes: W3Thi then W3Tlo (split-bf16 for f32-accurate Wm3)
    #pragma unroll
    for (int pass = 0; pass < 2; ++pass) {
        const unsigned short* W3T = pass == 0 ? W3Thi : W3Tlo;
        short8_t b[4][2];
        #pragma unroll
        for (int g = 0; g < 4; ++g)
            #pragma unroll
            for (int ks = 0; ks < 2; ++ks)
                b[g][ks] = *(const short8_t*)&W3T[(size_t)(g * 128 + w * 16 + l15) * 64 + ks * 32 + lk * 8];
        #pragma unroll
        for (int mf = 0; mf < 4; ++mf) {
            const int erow = 16 * (l15 >> 2) + 4 * mf + (l15 & 3);   // sigma
            const size_t rowb = (size_t)(ebase + erow) * 64;
            const short8_t a0 = *(const short8_t*)&hmS[rowb + lk * 8];
            const short8_t a1 = *(const short8_t*)&hmS[rowb + 32 + lk * 8];
            #pragma unroll
            for (int g = 0; g < 4; ++g) {
                acc[mf][g] = __builtin_amdgcn_mfma_f32_16x16x32_bf16(a0, b[g][0], acc[mf][g], 0, 0, 0);
                acc[mf][g] = __builtin_amdgcn_mfma_f32_16x16x32_bf16(a1, b[g][1], acc[mf][g], 0, 0, 0);
            }
        }
    }
    __syncthreads();

    // epilogue: lane owns col cidx and 16 CONSECUTIVE sorted edges lk*16 .. lk*16+15
    const int cidx = w * 16 + l15;
    float s0 = 0.f, s1 = 0.f, s2 = 0.f, s3 = 0.f, s4v = 0.f, s5 = 0.f, s6 = 0.f, s7 = 0.f;
    int cr = lrs[lk * 16];
    #pragma unroll
    for (int mf = 0; mf < 4; ++mf) {
        #pragma unroll
        for (int reg = 0; reg < 4; ++reg) {
            const int el = lk * 16 + mf * 4 + reg;   // = sigma(C-row mf*16+lk*4+reg)
            const int r = lrs[el];
            if (r != cr) {
                float* arow = Acat + (size_t)cr * 1024;
                atomicAdd(arow + cidx, s0);
                atomicAdd(arow + 128 + cidx, s1);
                atomicAdd(arow + 256 + cidx, s2);
                atomicAdd(arow + 512 + cidx, s3);
                atomicAdd(arow + 768 + cidx, s4v);
                atomicAdd(arow + 384 + cidx, s5);
                atomicAdd(arow + 640 + cidx, s6);
                atomicAdd(arow + 896 + cidx, s7);
                s0 = s1 = s2 = s3 = s4v = s5 = s6 = s7 = 0.f;
                cr = r;
            }
            const float4 Y = lY[el];
            const ushort4 hq = hb[(size_t)lss[el] * 128 + cidx];
            const float hx = bf2f(hq.x), hy = bf2f(hq.y), hz = bf2f(hq.z), hw = bf2f(hq.w);
            const float w0 = acc[mf][0][reg];
            const float w1 = acc[mf][1][reg];
            const float w2 = acc[mf][2][reg];
            const float w3 = acc[mf][3][reg];
            s0 += w0 * hx * Y.x;
            s1 += w1 * (hy * Y.y + hz * Y.z + hw * Y.w) * 0.5773502691896258f;
            const float m = w2 * hx;
            s2 += m * Y.y; s3 += m * Y.z; s4v += m * Y.w;
            const float m2 = w3 * Y.x;
            s5 += m2 * hy; s6 += m2 * hz; s7 += m2 * hw;
        }
    }
    {
        float* arow = Acat + (size_t)cr * 1024;
        atomicAdd(arow + cidx, s0);
        atomicAdd(arow + 128 + cidx, s1);
        atomicAdd(arow + 256 + cidx, s2);
        atomicAdd(arow + 512 + cidx, s3);
        atomicAdd(arow + 768 + cidx, s4v);
        atomicAdd(arow + 384 + cidx, s5);
        atomicAdd(arow + 640 + cidx, s6);
        atomicAdd(arow + 896 + cidx, s7);
    }
}

// ---------------- K4 (MFMA, split-bf16 both operands): o_d = Acat[:,d*256:+256] @ Wpost_d
// pass0: A_hi @ (W_hi + W_lo); pass1: A_lo @ W_hi. (A_lo@W_lo dropped; ~f32 accuracy.)
__global__ __launch_bounds__(256) void postom_kernel(const float* __restrict__ Acat,
                                                     const float* __restrict__ Wpost0,
                                                     const float* __restrict__ Wpost1,
                                                     float* __restrict__ o) {
    __shared__ unsigned short sA[128][256];   // 64 KB
    const int tid = threadIdx.x;
    const int d = blockIdx.y;
    const int nb = blockIdx.x * 128;
    const float* Wp = (d == 0) ? Wpost0 : Wpost1;

    const int wid = tid >> 6, lane = tid & 63;
    const int wr = wid >> 1, wc = wid & 1;
    const int l15 = lane & 15, lk = lane >> 4;

    f32x4 acc[4][4];
    #pragma unroll
    for (int mf = 0; mf < 4; ++mf)
        #pragma unroll
        for (int cf = 0; cf < 4; ++cf) acc[mf][cf] = (f32x4){0.f, 0.f, 0.f, 0.f};

    #pragma unroll
    for (int pass = 0; pass < 2; ++pass) {
        __syncthreads();
        {
            const int n = tid >> 1, half = tid & 1;
            const float4* src = (const float4*)(Acat + (size_t)(nb + n) * 1024 + (d << 8)) + half * 32;
            #pragma unroll
            for (int j = 0; j < 32; j += 2) {
                const float4 v0 = src[j];
                const float4 v1 = src[j + 1];
                const int k0 = (half * 128 + j * 4) ^ ((n & 7) << 3);
                union { unsigned short s[8]; uint4 q; } pk;
                const float f0[8] = {v0.x, v0.y, v0.z, v0.w, v1.x, v1.y, v1.z, v1.w};
                #pragma unroll
                for (int q = 0; q < 8; ++q) {
                    const unsigned short hi = f2bf(f0[q]);
                    pk.s[q] = (pass == 0) ? hi : f2bf(f0[q] - bf2f(hi));
                }
                *(uint4*)&sA[n][k0] = pk.q;
            }
        }
        __syncthreads();

        #pragma unroll
        for (int ks = 0; ks < 8; ++ks) {
            const int ku = ks * 32 + lk * 8;
            short8_t a[4];
            #pragma unroll
            for (int mf = 0; mf < 4; ++mf) {
                const int row = wr * 64 + mf * 16 + l15;
                a[mf] = *(const short8_t*)&sA[row][ku ^ ((row & 7) << 3)];
            }
            short8_t bh[4], bl[4];
            #pragma unroll
            for (int cf = 0; cf < 4; ++cf) {
                const int col = wc * 64 + cf * 16 + l15;
                union { unsigned short s[8]; short8_t v; } h, l;
                #pragma unroll
                for (int q = 0; q < 8; ++q) {
                    const float f = Wp[(size_t)(ku + q) * 128 + col];
                    const unsigned short hi = f2bf(f);
                    h.s[q] = hi;
                    l.s[q] = f2bf(f - bf2f(hi));
                }
                bh[cf] = h.v; bl[cf] = l.v;
            }
            #pragma unroll
            for (int mf = 0; mf < 4; ++mf)
                #pragma unroll
                for (int cf = 0; cf < 4; ++cf) {
                    acc[mf][cf] = __builtin_amdgcn_mfma_f32_16x16x32_bf16(a[mf], bh[cf], acc[mf][cf], 0, 0, 0);
                    if (pass == 0)
                        acc[mf][cf] = __builtin_amdgcn_mfma_f32_16x16x32_bf16(a[mf], bl[cf], acc[mf][cf], 0, 0, 0);
                }
        }
    }

    const float inv_2c = 0.0625f;
    #pragma unroll
    for (int mf = 0; mf < 4; ++mf) {
        #pragma unroll
        for (int j = 0; j < 4; ++j) {
            const int n = nb + wr * 64 + mf * 16 + lk * 4 + j;
            #pragma unroll
            for (int cf = 0; cf < 4; ++cf) {
                const int col = wc * 64 + cf * 16 + l15;
                o[((size_t)n * 4 + d) * 128 + col] = acc[mf][cf][j] * inv_2c;
            }
        }
    }
}

// ---------------- WaT: one-time transpose Wa(u,v,w) -> WaT[arr][v][w][u] bf16
__global__ __launch_bounds__(256) void watT_kernel(const float* __restrict__ Wa0,
                                                   const float* __restrict__ Wa1,
                                                   unsigned short* __restrict__ WaT) {
    __shared__ unsigned short tile[128][129];
    const int tid = threadIdx.x;
    const int v = blockIdx.x;
    const int arr = blockIdx.y;
    const float* Wa = (arr == 0) ? Wa0 : Wa1;
    {
        const int u = tid >> 1, half = tid & 1;
        const float4* src = (const float4*)(Wa + ((size_t)u * AA + v) * 128 + half * 64);
        #pragma unroll
        for (int j = 0; j < 16; ++j) {
            const float4 val = src[j];
            const int w = half * 64 + j * 4;
            tile[w + 0][u] = f2bf(val.x);
            tile[w + 1][u] = f2bf(val.y);
            tile[w + 2][u] = f2bf(val.z);
            tile[w + 3][u] = f2bf(val.w);
        }
    }
    __syncthreads();
    {
        const int w = tid >> 1, half = tid & 1;
        unsigned short* dst = WaT + (size_t)arr * 163840 + (size_t)v * 16384 + (size_t)w * 128;
        #pragma unroll
        for (int j = 0; j < 8; ++j) {
            const int u0 = half * 64 + j * 8;
            union { unsigned short s[8]; uint4 q; } pk;
            #pragma unroll
            for (int k = 0; k < 8; ++k) pk.s[k] = tile[w][u0 + k];
            *(uint4*)(dst + u0) = pk.q;
        }
    }
}

// ---------------- K5 (MFMA): out_d[n,w] = sum_v attr[n,v] * (o_d[n,:] @ Wa[:,v,:])
__global__ __launch_bounds__(256) void attrm_kernel(const float* __restrict__ o,
                                                    const float* __restrict__ attr,
                                                    const unsigned short* __restrict__ WaT,
                                                    float* __restrict__ tmp) {
    __shared__ unsigned short sA[128][128];
    __shared__ unsigned short sB[128][128];
    __shared__ float sat[128][AA];
    const int tid = threadIdx.x;
    const int d = blockIdx.y;
    const int nb = blockIdx.x * 128;
    const unsigned short* Wp = WaT + (d == 0 ? 0 : 163840);

    {
        const int n = tid >> 1, half = tid & 1;
        const float4* src = (const float4*)(o + ((size_t)(nb + n) * 4 + d) * 128 + half * 64);
        #pragma unroll
        for (int j = 0; j < 16; ++j) {
            const float4 val = src[j];
            const int u0 = (half * 64 + j * 4) ^ ((n & 7) << 3);
            u16x4 pk;
            pk.x = f2bf(val.x); pk.y = f2bf(val.y); pk.z = f2bf(val.z); pk.w = f2bf(val.w);
            *(u16x4*)&sA[n][u0] = pk;
        }
    }
    for (int i = tid; i < 128 * AA; i += 256) ((float*)sat)[i] = attr[(size_t)nb * AA + i];

    const int wid = tid >> 6, lane = tid & 63;
    const int wr = wid >> 1, wc = wid & 1;
    const int lrow = lane & 15, lk = lane >> 4;

    f32x4 tot[4][4];
    #pragma unroll
    for (int mf = 0; mf < 4; ++mf)
        #pragma unroll
        for (int cf = 0; cf < 4; ++cf) tot[mf][cf] = (f32x4){0.f, 0.f, 0.f, 0.f};

    for (int v = 0; v < AA; ++v) {
        __syncthreads();
        {
            const uint4* src = (const uint4*)(Wp + (size_t)v * 16384);
            #pragma unroll
            for (int j = 0; j < 8; ++j) {
                const int cidx = tid + j * 256;
                const int w = cidx >> 4;
                const int u0 = ((cidx & 15) * 8) ^ ((w & 7) << 3);
                const uint4 val = src[cidx];
                *(uint4*)&sB[w][u0] = val;
            }
        }
        __syncthreads();

        f32x4 acc[4][4];
        #pragma unroll
        for (int mf = 0; mf < 4; ++mf)
            #pragma unroll
            for (int cf = 0; cf < 4; ++cf) acc[mf][cf] = (f32x4){0.f, 0.f, 0.f, 0.f};

        #pragma unroll
        for (int ks = 0; ks < 4; ++ks) {
            const int ku = ks * 32 + lk * 8;
            short8_t a[4], b[4];
            #pragma unroll
            for (int mf = 0; mf < 4; ++mf) {
                const int row = wr * 64 + mf * 16 + lrow;
                a[mf] = *(const short8_t*)&sA[row][ku ^ ((row & 7) << 3)];
            }
            #pragma unroll
            for (int cf = 0; cf < 4; ++cf) {
                const int col = wc * 64 + cf * 16 + lrow;
                b[cf] = *(const short8_t*)&sB[col][ku ^ ((col & 7) << 3)];
            }
            #pragma unroll
            for (int mf = 0; mf < 4; ++mf)
                #pragma unroll
                for (int cf = 0; cf < 4; ++cf)
                    acc[mf][cf] = __builtin_amdgcn_mfma_f32_16x16x32_bf16(a[mf], b[cf], acc[mf][cf], 0, 0, 0);
        }

        #pragma unroll
        for (int mf = 0; mf < 4; ++mf) {
            const int row0 = wr * 64 + mf * 16 + lk * 4;
            #pragma unroll
            for (int j = 0; j < 4; ++j) {
                const float wj = sat[row0 + j][v];
                #pragma unroll
                for (int cf = 0; cf < 4; ++cf)
                    tot[mf][cf][j] += wj * acc[mf][cf][j];
            }
        }
    }

    const float inv_ca = 0.027950849718747373f;
    #pragma unroll
    for (int mf = 0; mf < 4; ++mf) {
        #pragma unroll
        for (int j = 0; j < 4; ++j) {
            const int n = nb + wr * 64 + mf * 16 + lk * 4 + j;
            #pragma unroll
            for (int cf = 0; cf < 4; ++cf) {
                const int col = wc * 64 + cf * 16 + lrow;
                tmp[(size_t)d * 2048000 + (size_t)n * 128 + col] = tot[mf][cf][j] * inv_ca;
            }
        }
    }
}

// ---------------- pack: out[n][w][0..3] = {tmp_d planes} as float4
__global__ __launch_bounds__(256) void pack_kernel(const float* __restrict__ tmp,
                                                   float4* __restrict__ out4) {
    const size_t e = (size_t)blockIdx.x * 256 + threadIdx.x;
    out4[e] = make_float4(tmp[e], tmp[2048000 + e], tmp[4096000 + e], tmp[6144000 + e]);
}

extern "C" void kernel_launch(void* const* d_in, const int* in_sizes, int n_in,
                              void* d_out, int out_size, void* d_ws, size_t ws_size,
                              hipStream_t stream) {
    const float* nf    = (const float*)d_in[0];
    const float* attr  = (const float*)d_in[1];
    const float* sph   = (const float*)d_in[2];
    const float* rb    = (const float*)d_in[3];
    const int*   ei    = (const int*)d_in[4];
    const float* Wpre0 = (const float*)d_in[5];
    const float* Wpre1 = (const float*)d_in[6];
    const float* Wm1   = (const float*)d_in[7];
    const float* Wm2   = (const float*)d_in[8];
    const float* Wm3   = (const float*)d_in[9];
    const float* Wpost0= (const float*)d_in[10];
    const float* Wpost1= (const float*)d_in[11];
    const float* Wa0   = (const float*)d_in[12];
    const float* Wa1   = (const float*)d_in[13];
    float* out = (float*)d_out;

    float* ws = (float*)d_ws;
    // footprint identical to R3/R4/R6/R9/R12/R16/R17 (proven): ends at Ys + 256000 float4
    ushort4* hb = (ushort4*)ws;                     // (N,128) ushort4 = 16 MB (first half of region 0)
    int* ipos = (int*)(ws + (size_t)4096000);      // 1 MB; dead after mlp; overwritten later by o
    unsigned short* hmS = (unsigned short*)(ws + (size_t)8192000);
    float* Acat = ws + (size_t)16384000;
    int* perm = (int*)(Acat + (size_t)16384000);  // 256000 ints; dead after gather
    int* cur  = perm + 256000;                     // 16384
    int* cnt  = cur + 16384;                       // 16384
    int* ss   = cnt + 16384;                       // 256000
    int* rs   = ss + 256000;                       // 256000
    float4* Ys = (float4*)(rs + 256000);           // 256000 float4 -- END of footprint
    unsigned short* W3Thi = (unsigned short*)perm; // 64 KB, reuses dead perm
    unsigned short* W3Tlo = W3Thi + 32768;         // 64 KB, still inside perm's 1 MB
    float* o = ws;                                  // (N,4,128) f32, aliases hb+ipos (dead after wmsgm/mlp)
    float* tmp = Acat;                              // 4 x 2,048,000 f32
    unsigned short* WaT = (unsigned short*)(Acat + (size_t)8192000);

    hipMemsetAsync(Acat, 0, (size_t)NN * 1024 * sizeof(float), stream);
    hipMemsetAsync(cnt, 0, 16384 * sizeof(int), stream);

    pre_kernel<<<NN / 2, 256, 0, stream>>>(nf, Wpre0, Wpre1, hb);
    count_kernel<<<EE / 256, 256, 0, stream>>>(ei, cnt);
    scan_kernel<<<1, 1024, 0, stream>>>(cnt, cur);
    fill_kernel<<<EE / 256, 256, 0, stream>>>(ei, cur, perm, ipos);
    gather_kernel<<<EE / 256, 256, 0, stream>>>(perm, ei, (const float4*)sph, ss, rs, Ys);
    mlp_kernel<<<EE / 256, 256, 0, stream>>>(rb, Wm1, Wm2, ipos, hmS);
    w3t_kernel<<<128, 256, 0, stream>>>(Wm3, W3Thi, W3Tlo);   // overwrites perm (dead)
    wmsgm_kernel<<<EE / 64, 512, 0, stream>>>(hmS, W3Thi, W3Tlo, ss, rs, Ys, hb, Acat);
    postom_kernel<<<dim3(NN / 128, 4), 256, 0, stream>>>(Acat, Wpost0, Wpost1, o);
    watT_kernel<<<dim3(AA, 2), 256, 0, stream>>>(Wa0, Wa1, WaT);
    attrm_kernel<<<dim3(NN / 128, 4), 256, 0, stream>>>(o, attr, WaT, tmp);
    pack_kernel<<<8000, 256, 0, stream>>>(tmp, (float4*)out);
}

// Round 21
// 598.430 us; speedup vs baseline: 1.0513x; 1.0513x over previous
//
#include <hip/hip_runtime.h>
#include <hip/hip_bf16.h>

#define NN 16000
#define CC 128
#define EE 256000
#define AA 10

typedef short short8_t __attribute__((ext_vector_type(8)));
typedef float f32x4 __attribute__((ext_vector_type(4)));
typedef unsigned short u16x4 __attribute__((ext_vector_type(4)));

__device__ __forceinline__ float silu_f(float x) {
    return x / (1.0f + __expf(-x));
}

__device__ __forceinline__ float bf2f(unsigned short u) {
    unsigned int x = ((unsigned int)u) << 16;
    float f;
    __builtin_memcpy(&f, &x, 4);
    return f;
}

__device__ __forceinline__ unsigned short f2bf(float f) {
    __hip_bfloat16 b = __float2bfloat16(f);
    unsigned short u;
    __builtin_memcpy(&u, &b, 2);
    return u;
}

// ---------------- K1: h0/h1 pre-linears -> hb (N,128) ushort4 bf16 [h0, h1x, h1y, h1z]
// 8 nodes/block: amortizes Wpre L2 traffic 8x vs 2 nodes/block (1.05 GB -> 131 MB).
__global__ __launch_bounds__(256) void pre_kernel(const float* __restrict__ nf,
                                                  const float* __restrict__ Wpre0,
                                                  const float* __restrict__ Wpre1,
                                                  ushort4* __restrict__ hb) {
    __shared__ float4 lx[8][CC];   // 16 KB
    const int tid = threadIdx.x;
    const int nb = blockIdx.x * 8;
    const float inv_c = 0.08838834764831843f;
    {
        const int nl = tid >> 5, lane32 = tid & 31;
        const float* row = nf + (size_t)(nb + nl) * 512;
        #pragma unroll
        for (int j = 0; j < 4; ++j) {
            const int c = lane32 + 32 * j;
            lx[nl][c] = make_float4(row[c], row[128 + 3 * c], row[128 + 3 * c + 1], row[128 + 3 * c + 2]);
        }
    }
    __syncthreads();
    const int c = tid & 127;
    const int g = tid >> 7;        // node group: nodes g*4 .. g*4+3
    float4 acc[4];
    #pragma unroll
    for (int k = 0; k < 4; ++k) acc[k] = make_float4(0.f, 0.f, 0.f, 0.f);
    #pragma unroll 4
    for (int u = 0; u < 128; ++u) {
        const float w0 = Wpre0[u * 128 + c];
        const float w1 = Wpre1[u * 128 + c];
        #pragma unroll
        for (int k = 0; k < 4; ++k) {
            const float4 xv = lx[g * 4 + k][u];
            acc[k].x += w0 * xv.x;
            acc[k].y += w1 * xv.y;
            acc[k].z += w1 * xv.z;
            acc[k].w += w1 * xv.w;
        }
    }
    #pragma unroll
    for (int k = 0; k < 4; ++k) {
        ushort4 o;
        o.x = f2bf(acc[k].x * inv_c);
        o.y = f2bf(acc[k].y * inv_c);
        o.z = f2bf(acc[k].z * inv_c);
        o.w = f2bf(acc[k].w * inv_c);
        hb[(size_t)(nb + g * 4 + k) * 128 + c] = o;
    }
}

// ---------------- CSR build: count -> scan -> fill perm+ipos (edges sorted by receiver)
__global__ __launch_bounds__(256) void count_kernel(const int* __restrict__ ei,
                                                    int* __restrict__ cnt) {
    const int e = blockIdx.x * 256 + threadIdx.x;
    if (e < EE) atomicAdd(&cnt[ei[EE + e]], 1);
}

__global__ __launch_bounds__(1024) void scan_kernel(const int* __restrict__ cnt,
                                                    int* __restrict__ cur) {
    __shared__ int part[1024];
    const int t = threadIdx.x;
    const int base = t * 16;
    int local[16];
    int s = 0;
    #pragma unroll
    for (int i = 0; i < 16; ++i) {
        const int idx = base + i;
        const int v = (idx < NN) ? cnt[idx] : 0;
        local[i] = s;
        s += v;
    }
    part[t] = s;
    __syncthreads();
    for (int off = 1; off < 1024; off <<= 1) {
        int v = (t >= off) ? part[t - off] : 0;
        __syncthreads();
        part[t] += v;
        __syncthreads();
    }
    const int pre = (t == 0) ? 0 : part[t - 1];
    #pragma unroll
    for (int i = 0; i < 16; ++i) {
        const int idx = base + i;
        if (idx < NN) cur[idx] = pre + local[i];
    }
}

__global__ __launch_bounds__(256) void fill_kernel(const int* __restrict__ ei,
                                                   int* __restrict__ cur,
                                                   int* __restrict__ perm,
                                                   int* __restrict__ ipos) {
    const int e = blockIdx.x * 256 + threadIdx.x;
    if (e < EE) {
        const int r = ei[EE + e];
        const int pos = atomicAdd(&cur[r], 1);
        perm[pos] = e;
        ipos[e] = pos;
    }
}

// ---------------- gather edge metadata into sorted order
__global__ __launch_bounds__(256) void gather_kernel(const int* __restrict__ perm,
                                                     const int* __restrict__ ei,
                                                     const float4* __restrict__ sph4,
                                                     int* __restrict__ ss,
                                                     int* __restrict__ rs,
                                                     float4* __restrict__ Ys) {
    const int e = blockIdx.x * 256 + threadIdx.x;
    const int p = perm[e];
    ss[e] = ei[p];
    rs[e] = ei[EE + p];
    Ys[e] = sph4[p];
}

// ---------------- K2: radial MLP in ORIGINAL order (coalesced rb) -> scatter full
// 128B bf16 rows to hmS[ipos[e]] (full-line writes: no RMW, no fetch amplification).
__global__ __launch_bounds__(256) void mlp_kernel(const float* __restrict__ rb,
                                                  const float* __restrict__ Wm1,
                                                  const float* __restrict__ Wm2,
                                                  const int* __restrict__ ipos,
                                                  unsigned short* __restrict__ hmS) {
    __shared__ float4 sW1[8][16];
    __shared__ float4 sW2[64][16];
    const int tid = threadIdx.x;
    for (int i = tid; i < 8 * 16; i += 256) ((float4*)sW1)[i] = ((const float4*)Wm1)[i];
    for (int i = tid; i < 64 * 16; i += 256) ((float4*)sW2)[i] = ((const float4*)Wm2)[i];
    __syncthreads();
    const int e = blockIdx.x * 256 + tid;
    const float4* rb4 = (const float4*)(rb + (size_t)e * 8);
    const float4 r0 = rb4[0], r1 = rb4[1];
    float r[8] = {r0.x, r0.y, r0.z, r0.w, r1.x, r1.y, r1.z, r1.w};
    float h1[64];
    #pragma unroll
    for (int o4 = 0; o4 < 16; ++o4) {
        float4 a = make_float4(0.f, 0.f, 0.f, 0.f);
        #pragma unroll
        for (int k = 0; k < 8; ++k) {
            const float4 wv = sW1[k][o4];
            a.x += r[k] * wv.x; a.y += r[k] * wv.y; a.z += r[k] * wv.z; a.w += r[k] * wv.w;
        }
        h1[o4 * 4 + 0] = silu_f(a.x);
        h1[o4 * 4 + 1] = silu_f(a.y);
        h1[o4 * 4 + 2] = silu_f(a.z);
        h1[o4 * 4 + 3] = silu_f(a.w);
    }
    union { unsigned short s[64]; uint4 q[8]; } buf;
    #pragma unroll
    for (int o4 = 0; o4 < 16; ++o4) {
        float4 a = make_float4(0.f, 0.f, 0.f, 0.f);
        #pragma unroll 8
        for (int k = 0; k < 64; ++k) {
            const float4 wv = sW2[k][o4];
            a.x += h1[k] * wv.x; a.y += h1[k] * wv.y; a.z += h1[k] * wv.z; a.w += h1[k] * wv.w;
        }
        buf.s[o4 * 4 + 0] = f2bf(silu_f(a.x));
        buf.s[o4 * 4 + 1] = f2bf(silu_f(a.y));
        buf.s[o4 * 4 + 2] = f2bf(silu_f(a.z));
        buf.s[o4 * 4 + 3] = f2bf(silu_f(a.w));
    }
    uint4* dst = (uint4*)(hmS + (size_t)ipos[e] * 64);
    #pragma unroll
    for (int j = 0; j < 8; ++j) dst[j] = buf.q[j];
}

// ---------------- prep: split-bf16 W3T: hi = bf16(W), lo = bf16(W - hi); layout [col][k]
__global__ __launch_bounds__(256) void w3t_kernel(const float* __restrict__ Wm3,
                                                  unsigned short* __restrict__ W3Thi,
                                                  unsigned short* __restrict__ W3Tlo) {
    const int idx = blockIdx.x * 256 + threadIdx.x;  // 0..32767
    const int col = idx >> 6, k = idx & 63;
    const float v = Wm3[k * 512 + col];
    const unsigned short hi = f2bf(v);
    W3Thi[idx] = hi;
    W3Tlo[idx] = f2bf(v - bf2f(hi));
}

// ---------------- K3 (MFMA): w-GEMM over sorted edges + fused messages, run-compressed
// atomics (R17-proven structure, UNMODIFIED).
__global__ __launch_bounds__(512) void wmsgm_kernel(const unsigned short* __restrict__ hmS,
                                                    const unsigned short* __restrict__ W3Thi,
                                                    const unsigned short* __restrict__ W3Tlo,
                                                    const int* __restrict__ ss,
                                                    const int* __restrict__ rs,
                                                    const float4* __restrict__ Ys,
                                                    const ushort4* __restrict__ hb,
                                                    float* __restrict__ Acat) {
    __shared__ int lss[64];
    __shared__ int lrs[64];
    __shared__ float4 lY[64];
    const int tid = threadIdx.x;
    const int ebase = blockIdx.x * 64;
    if (tid < 64) {
        lss[tid] = ss[ebase + tid];
        lrs[tid] = rs[ebase + tid];
        lY[tid] = Ys[ebase + tid];
    }
    const int w = tid >> 6, lane = tid & 63;
    const int l15 = lane & 15, lk = lane >> 4;

    f32x4 acc[4][4];
    #pragma unroll
    for (int mf = 0; mf < 4; ++mf)
        #pragma unroll
        for (int g = 0; g < 4; ++g) acc[mf][g] = (f32x4){0.f, 0.f, 0.f, 0.f};

    // two passes: W3Thi then W3Tlo (split-bf16 for f32-accurate Wm3)
    #pragma unroll
    for (int pass = 0; pass < 2; ++pass) {
        const unsigned short* W3T = pass == 0 ? W3Thi : W3Tlo;
        short8_t b[4][2];
        #pragma unroll
        for (int g = 0; g < 4; ++g)
            #pragma unroll
            for (int ks = 0; ks < 2; ++ks)
                b[g][ks] = *(const short8_t*)&W3T[(size_t)(g * 128 + w * 16 + l15) * 64 + ks * 32 + lk * 8];
        #pragma unroll
        for (int mf = 0; mf < 4; ++mf) {
            const int erow = 16 * (l15 >> 2) + 4 * mf + (l15 & 3);   // sigma
            const size_t rowb = (size_t)(ebase + erow) * 64;
            const short8_t a0 = *(const short8_t*)&hmS[rowb + lk * 8];
            const short8_t a1 = *(const short8_t*)&hmS[rowb + 32 + lk * 8];
            #pragma unroll
            for (int g = 0; g < 4; ++g) {
                acc[mf][g] = __builtin_amdgcn_mfma_f32_16x16x32_bf16(a0, b[g][0], acc[mf][g], 0, 0, 0);
                acc[mf][g] = __builtin_amdgcn_mfma_f32_16x16x32_bf16(a1, b[g][1], acc[mf][g], 0, 0, 0);
            }
        }
    }
    __syncthreads();

    // epilogue: lane owns col cidx and 16 CONSECUTIVE sorted edges lk*16 .. lk*16+15
    const int cidx = w * 16 + l15;
    float s0 = 0.f, s1 = 0.f, s2 = 0.f, s3 = 0.f, s4v = 0.f, s5 = 0.f, s6 = 0.f, s7 = 0.f;
    int cr = lrs[lk * 16];
    #pragma unroll
    for (int mf = 0; mf < 4; ++mf) {
        #pragma unroll
        for (int reg = 0; reg < 4; ++reg) {
            const int el = lk * 16 + mf * 4 + reg;   // = sigma(C-row mf*16+lk*4+reg)
            const int r = lrs[el];
            if (r != cr) {
                float* arow = Acat + (size_t)cr * 1024;
                atomicAdd(arow + cidx, s0);
                atomicAdd(arow + 128 + cidx, s1);
                atomicAdd(arow + 256 + cidx, s2);
                atomicAdd(arow + 512 + cidx, s3);
                atomicAdd(arow + 768 + cidx, s4v);
                atomicAdd(arow + 384 + cidx, s5);
                atomicAdd(arow + 640 + cidx, s6);
                atomicAdd(arow + 896 + cidx, s7);
                s0 = s1 = s2 = s3 = s4v = s5 = s6 = s7 = 0.f;
                cr = r;
            }
            const float4 Y = lY[el];
            const ushort4 hq = hb[(size_t)lss[el] * 128 + cidx];
            const float hx = bf2f(hq.x), hy = bf2f(hq.y), hz = bf2f(hq.z), hw = bf2f(hq.w);
            const float w0 = acc[mf][0][reg];
            const float w1 = acc[mf][1][reg];
            const float w2 = acc[mf][2][reg];
            const float w3 = acc[mf][3][reg];
            s0 += w0 * hx * Y.x;
            s1 += w1 * (hy * Y.y + hz * Y.z + hw * Y.w) * 0.5773502691896258f;
            const float m = w2 * hx;
            s2 += m * Y.y; s3 += m * Y.z; s4v += m * Y.w;
            const float m2 = w3 * Y.x;
            s5 += m2 * hy; s6 += m2 * hz; s7 += m2 * hw;
        }
    }
    {
        float* arow = Acat + (size_t)cr * 1024;
        atomicAdd(arow + cidx, s0);
        atomicAdd(arow + 128 + cidx, s1);
        atomicAdd(arow + 256 + cidx, s2);
        atomicAdd(arow + 512 + cidx, s3);
        atomicAdd(arow + 768 + cidx, s4v);
        atomicAdd(arow + 384 + cidx, s5);
        atomicAdd(arow + 640 + cidx, s6);
        atomicAdd(arow + 896 + cidx, s7);
    }
}

// ---------------- K4 (MFMA, split-bf16 both operands): o_d = Acat[:,d*256:+256] @ Wpost_d
// pass0: A_hi @ (W_hi + W_lo); pass1: A_lo @ W_hi. (A_lo@W_lo dropped; ~f32 accuracy.)
__global__ __launch_bounds__(256) void postom_kernel(const float* __restrict__ Acat,
                                                     const float* __restrict__ Wpost0,
                                                     const float* __restrict__ Wpost1,
                                                     float* __restrict__ o) {
    __shared__ unsigned short sA[128][256];   // 64 KB
    const int tid = threadIdx.x;
    const int d = blockIdx.y;
    const int nb = blockIdx.x * 128;
    const float* Wp = (d == 0) ? Wpost0 : Wpost1;

    const int wid = tid >> 6, lane = tid & 63;
    const int wr = wid >> 1, wc = wid & 1;
    const int l15 = lane & 15, lk = lane >> 4;

    f32x4 acc[4][4];
    #pragma unroll
    for (int mf = 0; mf < 4; ++mf)
        #pragma unroll
        for (int cf = 0; cf < 4; ++cf) acc[mf][cf] = (f32x4){0.f, 0.f, 0.f, 0.f};

    #pragma unroll
    for (int pass = 0; pass < 2; ++pass) {
        __syncthreads();
        {
            const int n = tid >> 1, half = tid & 1;
            const float4* src = (const float4*)(Acat + (size_t)(nb + n) * 1024 + (d << 8)) + half * 32;
            #pragma unroll
            for (int j = 0; j < 32; j += 2) {
                const float4 v0 = src[j];
                const float4 v1 = src[j + 1];
                const int k0 = (half * 128 + j * 4) ^ ((n & 7) << 3);
                union { unsigned short s[8]; uint4 q; } pk;
                const float f0[8] = {v0.x, v0.y, v0.z, v0.w, v1.x, v1.y, v1.z, v1.w};
                #pragma unroll
                for (int q = 0; q < 8; ++q) {
                    const unsigned short hi = f2bf(f0[q]);
                    pk.s[q] = (pass == 0) ? hi : f2bf(f0[q] - bf2f(hi));
                }
                *(uint4*)&sA[n][k0] = pk.q;
            }
        }
        __syncthreads();

        #pragma unroll
        for (int ks = 0; ks < 8; ++ks) {
            const int ku = ks * 32 + lk * 8;
            short8_t a[4];
            #pragma unroll
            for (int mf = 0; mf < 4; ++mf) {
                const int row = wr * 64 + mf * 16 + l15;
                a[mf] = *(const short8_t*)&sA[row][ku ^ ((row & 7) << 3)];
            }
            short8_t bh[4], bl[4];
            #pragma unroll
            for (int cf = 0; cf < 4; ++cf) {
                const int col = wc * 64 + cf * 16 + l15;
                union { unsigned short s[8]; short8_t v; } h, l;
                #pragma unroll
                for (int q = 0; q < 8; ++q) {
                    const float f = Wp[(size_t)(ku + q) * 128 + col];
                    const unsigned short hi = f2bf(f);
                    h.s[q] = hi;
                    l.s[q] = f2bf(f - bf2f(hi));
                }
                bh[cf] = h.v; bl[cf] = l.v;
            }
            #pragma unroll
            for (int mf = 0; mf < 4; ++mf)
                #pragma unroll
                for (int cf = 0; cf < 4; ++cf) {
                    acc[mf][cf] = __builtin_amdgcn_mfma_f32_16x16x32_bf16(a[mf], bh[cf], acc[mf][cf], 0, 0, 0);
                    if (pass == 0)
                        acc[mf][cf] = __builtin_amdgcn_mfma_f32_16x16x32_bf16(a[mf], bl[cf], acc[mf][cf], 0, 0, 0);
                }
        }
    }

    const float inv_2c = 0.0625f;
    #pragma unroll
    for (int mf = 0; mf < 4; ++mf) {
        #pragma unroll
        for (int j = 0; j < 4; ++j) {
            const int n = nb + wr * 64 + mf * 16 + lk * 4 + j;
            #pragma unroll
            for (int cf = 0; cf < 4; ++cf) {
                const int col = wc * 64 + cf * 16 + l15;
                o[((size_t)n * 4 + d) * 128 + col] = acc[mf][cf][j] * inv_2c;
            }
        }
    }
}

// ---------------- WaT: one-time transpose Wa(u,v,w) -> WaT[arr][v][w][u] bf16
__global__ __launch_bounds__(256) void watT_kernel(const float* __restrict__ Wa0,
                                                   const float* __restrict__ Wa1,
                                                   unsigned short* __restrict__ WaT) {
    __shared__ unsigned short tile[128][129];
    const int tid = threadIdx.x;
    const int v = blockIdx.x;
    const int arr = blockIdx.y;
    const float* Wa = (arr == 0) ? Wa0 : Wa1;
    {
        const int u = tid >> 1, half = tid & 1;
        const float4* src = (const float4*)(Wa + ((size_t)u * AA + v) * 128 + half * 64);
        #pragma unroll
        for (int j = 0; j < 16; ++j) {
            const float4 val = src[j];
            const int w = half * 64 + j * 4;
            tile[w + 0][u] = f2bf(val.x);
            tile[w + 1][u] = f2bf(val.y);
            tile[w + 2][u] = f2bf(val.z);
            tile[w + 3][u] = f2bf(val.w);
        }
    }
    __syncthreads();
    {
        const int w = tid >> 1, half = tid & 1;
        unsigned short* dst = WaT + (size_t)arr * 163840 + (size_t)v * 16384 + (size_t)w * 128;
        #pragma unroll
        for (int j = 0; j < 8; ++j) {
            const int u0 = half * 64 + j * 8;
            union { unsigned short s[8]; uint4 q; } pk;
            #pragma unroll
            for (int k = 0; k < 8; ++k) pk.s[k] = tile[w][u0 + k];
            *(uint4*)(dst + u0) = pk.q;
        }
    }
}

// ---------------- K5 (MFMA): out_d[n,w] = sum_v attr[n,v] * (o_d[n,:] @ Wa[:,v,:])
__global__ __launch_bounds__(256) void attrm_kernel(const float* __restrict__ o,
                                                    const float* __restrict__ attr,
                                                    const unsigned short* __restrict__ WaT,
                                                    float* __restrict__ tmp) {
    __shared__ unsigned short sA[128][128];
    __shared__ unsigned short sB[128][128];
    __shared__ float sat[128][AA];
    const int tid = threadIdx.x;
    const int d = blockIdx.y;
    const int nb = blockIdx.x * 128;
    const unsigned short* Wp = WaT + (d == 0 ? 0 : 163840);

    {
        const int n = tid >> 1, half = tid & 1;
        const float4* src = (const float4*)(o + ((size_t)(nb + n) * 4 + d) * 128 + half * 64);
        #pragma unroll
        for (int j = 0; j < 16; ++j) {
            const float4 val = src[j];
            const int u0 = (half * 64 + j * 4) ^ ((n & 7) << 3);
            u16x4 pk;
            pk.x = f2bf(val.x); pk.y = f2bf(val.y); pk.z = f2bf(val.z); pk.w = f2bf(val.w);
            *(u16x4*)&sA[n][u0] = pk;
        }
    }
    for (int i = tid; i < 128 * AA; i += 256) ((float*)sat)[i] = attr[(size_t)nb * AA + i];

    const int wid = tid >> 6, lane = tid & 63;
    const int wr = wid >> 1, wc = wid & 1;
    const int lrow = lane & 15, lk = lane >> 4;

    f32x4 tot[4][4];
    #pragma unroll
    for (int mf = 0; mf < 4; ++mf)
        #pragma unroll
        for (int cf = 0; cf < 4; ++cf) tot[mf][cf] = (f32x4){0.f, 0.f, 0.f, 0.f};

    for (int v = 0; v < AA; ++v) {
        __syncthreads();
        {
            const uint4* src = (const uint4*)(Wp + (size_t)v * 16384);
            #pragma unroll
            for (int j = 0; j < 8; ++j) {
                const int cidx = tid + j * 256;
                const int w = cidx >> 4;
                const int u0 = ((cidx & 15) * 8) ^ ((w & 7) << 3);
                const uint4 val = src[cidx];
                *(uint4*)&sB[w][u0] = val;
            }
        }
        __syncthreads();

        f32x4 acc[4][4];
        #pragma unroll
        for (int mf = 0; mf < 4; ++mf)
            #pragma unroll
            for (int cf = 0; cf < 4; ++cf) acc[mf][cf] = (f32x4){0.f, 0.f, 0.f, 0.f};

        #pragma unroll
        for (int ks = 0; ks < 4; ++ks) {
            const int ku = ks * 32 + lk * 8;
            short8_t a[4], b[4];
            #pragma unroll
            for (int mf = 0; mf < 4; ++mf) {
                const int row = wr * 64 + mf * 16 + lrow;
                a[mf] = *(const short8_t*)&sA[row][ku ^ ((row & 7) << 3)];
            }
            #pragma unroll
            for (int cf = 0; cf < 4; ++cf) {
                const int col = wc * 64 + cf * 16 + lrow;
                b[cf] = *(const short8_t*)&sB[col][ku ^ ((col & 7) << 3)];
            }
            #pragma unroll
            for (int mf = 0; mf < 4; ++mf)
                #pragma unroll
                for (int cf = 0; cf < 4; ++cf)
                    acc[mf][cf] = __builtin_amdgcn_mfma_f32_16x16x32_bf16(a[mf], b[cf], acc[mf][cf], 0, 0, 0);
        }

        #pragma unroll
        for (int mf = 0; mf < 4; ++mf) {
            const int row0 = wr * 64 + mf * 16 + lk * 4;
            #pragma unroll
            for (int j = 0; j < 4; ++j) {
                const float wj = sat[row0 + j][v];
                #pragma unroll
                for (int cf = 0; cf < 4; ++cf)
                    tot[mf][cf][j] += wj * acc[mf][cf][j];
            }
        }
    }

    const float inv_ca = 0.027950849718747373f;
    #pragma unroll
    for (int mf = 0; mf < 4; ++mf) {
        #pragma unroll
        for (int j = 0; j < 4; ++j) {
            const int n = nb + wr * 64 + mf * 16 + lk * 4 + j;
            #pragma unroll
            for (int cf = 0; cf < 4; ++cf) {
                const int col = wc * 64 + cf * 16 + lrow;
                tmp[(size_t)d * 2048000 + (size_t)n * 128 + col] = tot[mf][cf][j] * inv_ca;
            }
        }
    }
}

// ---------------- pack: out[n][w][0..3] = {tmp_d planes} as float4
__global__ __launch_bounds__(256) void pack_kernel(const float* __restrict__ tmp,
                                                   float4* __restrict__ out4) {
    const size_t e = (size_t)blockIdx.x * 256 + threadIdx.x;
    out4[e] = make_float4(tmp[e], tmp[2048000 + e], tmp[4096000 + e], tmp[6144000 + e]);
}

extern "C" void kernel_launch(void* const* d_in, const int* in_sizes, int n_in,
                              void* d_out, int out_size, void* d_ws, size_t ws_size,
                              hipStream_t stream) {
    const float* nf    = (const float*)d_in[0];
    const float* attr  = (const float*)d_in[1];
    const float* sph   = (const float*)d_in[2];
    const float* rb    = (const float*)d_in[3];
    const int*   ei    = (const int*)d_in[4];
    const float* Wpre0 = (const float*)d_in[5];
    const float* Wpre1 = (const float*)d_in[6];
    const float* Wm1   = (const float*)d_in[7];
    const float* Wm2   = (const float*)d_in[8];
    const float* Wm3   = (const float*)d_in[9];
    const float* Wpost0= (const float*)d_in[10];
    const float* Wpost1= (const float*)d_in[11];
    const float* Wa0   = (const float*)d_in[12];
    const float* Wa1   = (const float*)d_in[13];
    float* out = (float*)d_out;

    float* ws = (float*)d_ws;
    // footprint identical to R3/R4/R6/R9/R12/R16/R17/R20 (proven): ends at Ys + 256000 float4
    ushort4* hb = (ushort4*)ws;                     // (N,128) ushort4 = 16 MB (first half of region 0)
    int* ipos = (int*)(ws + (size_t)4096000);      // 1 MB; dead after mlp; overwritten later by o
    unsigned short* hmS = (unsigned short*)(ws + (size_t)8192000);
    float* Acat = ws + (size_t)16384000;
    int* perm = (int*)(Acat + (size_t)16384000);  // 256000 ints; dead after gather
    int* cur  = perm + 256000;                     // 16384
    int* cnt  = cur + 16384;                       // 16384
    int* ss   = cnt + 16384;                       // 256000
    int* rs   = ss + 256000;                       // 256000
    float4* Ys = (float4*)(rs + 256000);           // 256000 float4 -- END of footprint
    unsigned short* W3Thi = (unsigned short*)perm; // 64 KB, reuses dead perm
    unsigned short* W3Tlo = W3Thi + 32768;         // 64 KB, still inside perm's 1 MB
    float* o = ws;                                  // (N,4,128) f32, aliases hb+ipos (dead after wmsgm/mlp)
    float* tmp = Acat;                              // 4 x 2,048,000 f32
    unsigned short* WaT = (unsigned short*)(Acat + (size_t)8192000);

    hipMemsetAsync(Acat, 0, (size_t)NN * 1024 * sizeof(float), stream);
    hipMemsetAsync(cnt, 0, 16384 * sizeof(int), stream);

    pre_kernel<<<NN / 8, 256, 0, stream>>>(nf, Wpre0, Wpre1, hb);
    count_kernel<<<EE / 256, 256, 0, stream>>>(ei, cnt);
    scan_kernel<<<1, 1024, 0, stream>>>(cnt, cur);
    fill_kernel<<<EE / 256, 256, 0, stream>>>(ei, cur, perm, ipos);
    gather_kernel<<<EE / 256, 256, 0, stream>>>(perm, ei, (const float4*)sph, ss, rs, Ys);
    mlp_kernel<<<EE / 256, 256, 0, stream>>>(rb, Wm1, Wm2, ipos, hmS);
    w3t_kernel<<<128, 256, 0, stream>>>(Wm3, W3Thi, W3Tlo);   // overwrites perm (dead)
    wmsgm_kernel<<<EE / 64, 512, 0, stream>>>(hmS, W3Thi, W3Tlo, ss, rs, Ys, hb, Acat);
    postom_kernel<<<dim3(NN / 128, 4), 256, 0, stream>>>(Acat, Wpost0, Wpost1, o);
    watT_kernel<<<dim3(AA, 2), 256, 0, stream>>>(Wa0, Wa1, WaT);
    attrm_kernel<<<dim3(NN / 128, 4), 256, 0, stream>>>(o, attr, WaT, tmp);
    pack_kernel<<<8000, 256, 0, stream>>>(tmp, (float4*)out);
}

// Round 22
// 594.356 us; speedup vs baseline: 1.0585x; 1.0069x over previous
//
#include <hip/hip_runtime.h>
#include <hip/hip_bf16.h>

#define NN 16000
#define CC 128
#define EE 256000
#define AA 10

typedef short short8_t __attribute__((ext_vector_type(8)));
typedef float f32x4 __attribute__((ext_vector_type(4)));
typedef unsigned short u16x4 __attribute__((ext_vector_type(4)));

__device__ __forceinline__ float silu_f(float x) {
    return x / (1.0f + __expf(-x));
}

__device__ __forceinline__ float bf2f(unsigned short u) {
    unsigned int x = ((unsigned int)u) << 16;
    float f;
    __builtin_memcpy(&f, &x, 4);
    return f;
}

__device__ __forceinline__ unsigned short f2bf(float f) {
    __hip_bfloat16 b = __float2bfloat16(f);
    unsigned short u;
    __builtin_memcpy(&u, &b, 2);
    return u;
}

// ---------------- K1: h0/h1 pre-linears -> hb (N,128) ushort4 bf16 [h0, h1x, h1y, h1z]
// 8 nodes/block: amortizes Wpre L2 traffic 8x.
__global__ __launch_bounds__(256) void pre_kernel(const float* __restrict__ nf,
                                                  const float* __restrict__ Wpre0,
                                                  const float* __restrict__ Wpre1,
                                                  ushort4* __restrict__ hb) {
    __shared__ float4 lx[8][CC];   // 16 KB
    const int tid = threadIdx.x;
    const int nb = blockIdx.x * 8;
    const float inv_c = 0.08838834764831843f;
    {
        const int nl = tid >> 5, lane32 = tid & 31;
        const float* row = nf + (size_t)(nb + nl) * 512;
        #pragma unroll
        for (int j = 0; j < 4; ++j) {
            const int c = lane32 + 32 * j;
            lx[nl][c] = make_float4(row[c], row[128 + 3 * c], row[128 + 3 * c + 1], row[128 + 3 * c + 2]);
        }
    }
    __syncthreads();
    const int c = tid & 127;
    const int g = tid >> 7;        // node group: nodes g*4 .. g*4+3
    float4 acc[4];
    #pragma unroll
    for (int k = 0; k < 4; ++k) acc[k] = make_float4(0.f, 0.f, 0.f, 0.f);
    #pragma unroll 4
    for (int u = 0; u < 128; ++u) {
        const float w0 = Wpre0[u * 128 + c];
        const float w1 = Wpre1[u * 128 + c];
        #pragma unroll
        for (int k = 0; k < 4; ++k) {
            const float4 xv = lx[g * 4 + k][u];
            acc[k].x += w0 * xv.x;
            acc[k].y += w1 * xv.y;
            acc[k].z += w1 * xv.z;
            acc[k].w += w1 * xv.w;
        }
    }
    #pragma unroll
    for (int k = 0; k < 4; ++k) {
        ushort4 o;
        o.x = f2bf(acc[k].x * inv_c);
        o.y = f2bf(acc[k].y * inv_c);
        o.z = f2bf(acc[k].z * inv_c);
        o.w = f2bf(acc[k].w * inv_c);
        hb[(size_t)(nb + g * 4 + k) * 128 + c] = o;
    }
}

// ---------------- CSR build: count -> scan -> fill perm+ipos (edges sorted by receiver)
__global__ __launch_bounds__(256) void count_kernel(const int* __restrict__ ei,
                                                    int* __restrict__ cnt) {
    const int e = blockIdx.x * 256 + threadIdx.x;
    if (e < EE) atomicAdd(&cnt[ei[EE + e]], 1);
}

__global__ __launch_bounds__(1024) void scan_kernel(const int* __restrict__ cnt,
                                                    int* __restrict__ cur) {
    __shared__ int part[1024];
    const int t = threadIdx.x;
    const int base = t * 16;
    int local[16];
    int s = 0;
    #pragma unroll
    for (int i = 0; i < 16; ++i) {
        const int idx = base + i;
        const int v = (idx < NN) ? cnt[idx] : 0;
        local[i] = s;
        s += v;
    }
    part[t] = s;
    __syncthreads();
    for (int off = 1; off < 1024; off <<= 1) {
        int v = (t >= off) ? part[t - off] : 0;
        __syncthreads();
        part[t] += v;
        __syncthreads();
    }
    const int pre = (t == 0) ? 0 : part[t - 1];
    #pragma unroll
    for (int i = 0; i < 16; ++i) {
        const int idx = base + i;
        if (idx < NN) cur[idx] = pre + local[i];
    }
}

__global__ __launch_bounds__(256) void fill_kernel(const int* __restrict__ ei,
                                                   int* __restrict__ cur,
                                                   int* __restrict__ perm,
                                                   int* __restrict__ ipos) {
    const int e = blockIdx.x * 256 + threadIdx.x;
    if (e < EE) {
        const int r = ei[EE + e];
        const int pos = atomicAdd(&cur[r], 1);
        perm[pos] = e;
        ipos[e] = pos;
    }
}

// ---------------- gather edge metadata into sorted order
__global__ __launch_bounds__(256) void gather_kernel(const int* __restrict__ perm,
                                                     const int* __restrict__ ei,
                                                     const float4* __restrict__ sph4,
                                                     int* __restrict__ ss,
                                                     int* __restrict__ rs,
                                                     float4* __restrict__ Ys) {
    const int e = blockIdx.x * 256 + threadIdx.x;
    const int p = perm[e];
    ss[e] = ei[p];
    rs[e] = ei[EE + p];
    Ys[e] = sph4[p];
}

// ---------------- K2: radial MLP in ORIGINAL order (coalesced rb) -> scatter full
// 128B bf16 rows to hmS[ipos[e]] (full-line writes: no RMW, no fetch amplification).
__global__ __launch_bounds__(256) void mlp_kernel(const float* __restrict__ rb,
                                                  const float* __restrict__ Wm1,
                                                  const float* __restrict__ Wm2,
                                                  const int* __restrict__ ipos,
                                                  unsigned short* __restrict__ hmS) {
    __shared__ float4 sW1[8][16];
    __shared__ float4 sW2[64][16];
    const int tid = threadIdx.x;
    for (int i = tid; i < 8 * 16; i += 256) ((float4*)sW1)[i] = ((const float4*)Wm1)[i];
    for (int i = tid; i < 64 * 16; i += 256) ((float4*)sW2)[i] = ((const float4*)Wm2)[i];
    __syncthreads();
    const int e = blockIdx.x * 256 + tid;
    const float4* rb4 = (const float4*)(rb + (size_t)e * 8);
    const float4 r0 = rb4[0], r1 = rb4[1];
    float r[8] = {r0.x, r0.y, r0.z, r0.w, r1.x, r1.y, r1.z, r1.w};
    float h1[64];
    #pragma unroll
    for (int o4 = 0; o4 < 16; ++o4) {
        float4 a = make_float4(0.f, 0.f, 0.f, 0.f);
        #pragma unroll
        for (int k = 0; k < 8; ++k) {
            const float4 wv = sW1[k][o4];
            a.x += r[k] * wv.x; a.y += r[k] * wv.y; a.z += r[k] * wv.z; a.w += r[k] * wv.w;
        }
        h1[o4 * 4 + 0] = silu_f(a.x);
        h1[o4 * 4 + 1] = silu_f(a.y);
        h1[o4 * 4 + 2] = silu_f(a.z);
        h1[o4 * 4 + 3] = silu_f(a.w);
    }
    union { unsigned short s[64]; uint4 q[8]; } buf;
    #pragma unroll
    for (int o4 = 0; o4 < 16; ++o4) {
        float4 a = make_float4(0.f, 0.f, 0.f, 0.f);
        #pragma unroll 8
        for (int k = 0; k < 64; ++k) {
            const float4 wv = sW2[k][o4];
            a.x += h1[k] * wv.x; a.y += h1[k] * wv.y; a.z += h1[k] * wv.z; a.w += h1[k] * wv.w;
        }
        buf.s[o4 * 4 + 0] = f2bf(silu_f(a.x));
        buf.s[o4 * 4 + 1] = f2bf(silu_f(a.y));
        buf.s[o4 * 4 + 2] = f2bf(silu_f(a.z));
        buf.s[o4 * 4 + 3] = f2bf(silu_f(a.w));
    }
    uint4* dst = (uint4*)(hmS + (size_t)ipos[e] * 64);
    #pragma unroll
    for (int j = 0; j < 8; ++j) dst[j] = buf.q[j];
}

// ---------------- prep: split-bf16 W3T: hi = bf16(W), lo = bf16(W - hi); layout [col][k]
__global__ __launch_bounds__(256) void w3t_kernel(const float* __restrict__ Wm3,
                                                  unsigned short* __restrict__ W3Thi,
                                                  unsigned short* __restrict__ W3Tlo) {
    const int idx = blockIdx.x * 256 + threadIdx.x;  // 0..32767
    const int col = idx >> 6, k = idx & 63;
    const float v = Wm3[k * 512 + col];
    const unsigned short hi = f2bf(v);
    W3Thi[idx] = hi;
    W3Tlo[idx] = f2bf(v - bf2f(hi));
}

// ---------------- K3 (MFMA): w-GEMM over sorted edges + fused messages, run-compressed
// atomics (R17-proven structure, UNMODIFIED).
__global__ __launch_bounds__(512) void wmsgm_kernel(const unsigned short* __restrict__ hmS,
                                                    const unsigned short* __restrict__ W3Thi,
                                                    const unsigned short* __restrict__ W3Tlo,
                                                    const int* __restrict__ ss,
                                                    const int* __restrict__ rs,
                                                    const float4* __restrict__ Ys,
                                                    const ushort4* __restrict__ hb,
                                                    float* __restrict__ Acat) {
    __shared__ int lss[64];
    __shared__ int lrs[64];
    __shared__ float4 lY[64];
    const int tid = threadIdx.x;
    const int ebase = blockIdx.x * 64;
    if (tid < 64) {
        lss[tid] = ss[ebase + tid];
        lrs[tid] = rs[ebase + tid];
        lY[tid] = Ys[ebase + tid];
    }
    const int w = tid >> 6, lane = tid & 63;
    const int l15 = lane & 15, lk = lane >> 4;

    f32x4 acc[4][4];
    #pragma unroll
    for (int mf = 0; mf < 4; ++mf)
        #pragma unroll
        for (int g = 0; g < 4; ++g) acc[mf][g] = (f32x4){0.f, 0.f, 0.f, 0.f};

    // two passes: W3Thi then W3Tlo (split-bf16 for f32-accurate Wm3)
    #pragma unroll
    for (int pass = 0; pass < 2; ++pass) {
        const unsigned short* W3T = pass == 0 ? W3Thi : W3Tlo;
        short8_t b[4][2];
        #pragma unroll
        for (int g = 0; g < 4; ++g)
            #pragma unroll
            for (int ks = 0; ks < 2; ++ks)
                b[g][ks] = *(const short8_t*)&W3T[(size_t)(g * 128 + w * 16 + l15) * 64 + ks * 32 + lk * 8];
        #pragma unroll
        for (int mf = 0; mf < 4; ++mf) {
            const int erow = 16 * (l15 >> 2) + 4 * mf + (l15 & 3);   // sigma
            const size_t rowb = (size_t)(ebase + erow) * 64;
            const short8_t a0 = *(const short8_t*)&hmS[rowb + lk * 8];
            const short8_t a1 = *(const short8_t*)&hmS[rowb + 32 + lk * 8];
            #pragma unroll
            for (int g = 0; g < 4; ++g) {
                acc[mf][g] = __builtin_amdgcn_mfma_f32_16x16x32_bf16(a0, b[g][0], acc[mf][g], 0, 0, 0);
                acc[mf][g] = __builtin_amdgcn_mfma_f32_16x16x32_bf16(a1, b[g][1], acc[mf][g], 0, 0, 0);
            }
        }
    }
    __syncthreads();

    // epilogue: lane owns col cidx and 16 CONSECUTIVE sorted edges lk*16 .. lk*16+15
    const int cidx = w * 16 + l15;
    float s0 = 0.f, s1 = 0.f, s2 = 0.f, s3 = 0.f, s4v = 0.f, s5 = 0.f, s6 = 0.f, s7 = 0.f;
    int cr = lrs[lk * 16];
    #pragma unroll
    for (int mf = 0; mf < 4; ++mf) {
        #pragma unroll
        for (int reg = 0; reg < 4; ++reg) {
            const int el = lk * 16 + mf * 4 + reg;   // = sigma(C-row mf*16+lk*4+reg)
            const int r = lrs[el];
            if (r != cr) {
                float* arow = Acat + (size_t)cr * 1024;
                atomicAdd(arow + cidx, s0);
                atomicAdd(arow + 128 + cidx, s1);
                atomicAdd(arow + 256 + cidx, s2);
                atomicAdd(arow + 512 + cidx, s3);
                atomicAdd(arow + 768 + cidx, s4v);
                atomicAdd(arow + 384 + cidx, s5);
                atomicAdd(arow + 640 + cidx, s6);
                atomicAdd(arow + 896 + cidx, s7);
                s0 = s1 = s2 = s3 = s4v = s5 = s6 = s7 = 0.f;
                cr = r;
            }
            const float4 Y = lY[el];
            const ushort4 hq = hb[(size_t)lss[el] * 128 + cidx];
            const float hx = bf2f(hq.x), hy = bf2f(hq.y), hz = bf2f(hq.z), hw = bf2f(hq.w);
            const float w0 = acc[mf][0][reg];
            const float w1 = acc[mf][1][reg];
            const float w2 = acc[mf][2][reg];
            const float w3 = acc[mf][3][reg];
            s0 += w0 * hx * Y.x;
            s1 += w1 * (hy * Y.y + hz * Y.z + hw * Y.w) * 0.5773502691896258f;
            const float m = w2 * hx;
            s2 += m * Y.y; s3 += m * Y.z; s4v += m * Y.w;
            const float m2 = w3 * Y.x;
            s5 += m2 * hy; s6 += m2 * hz; s7 += m2 * hw;
        }
    }
    {
        float* arow = Acat + (size_t)cr * 1024;
        atomicAdd(arow + cidx, s0);
        atomicAdd(arow + 128 + cidx, s1);
        atomicAdd(arow + 256 + cidx, s2);
        atomicAdd(arow + 512 + cidx, s3);
        atomicAdd(arow + 768 + cidx, s4v);
        atomicAdd(arow + 384 + cidx, s5);
        atomicAdd(arow + 640 + cidx, s6);
        atomicAdd(arow + 896 + cidx, s7);
    }
}

// ---------------- K4 (MFMA, split-bf16 both operands): o_d = Acat[:,d*256:+256] @ Wpost_d
// pass0: A_hi @ (W_hi + W_lo); pass1: A_lo @ W_hi. Output o stored as bf16 (attrm
// rounds to bf16 anyway -> identical final values, half the o traffic).
__global__ __launch_bounds__(256) void postom_kernel(const float* __restrict__ Acat,
                                                     const float* __restrict__ Wpost0,
                                                     const float* __restrict__ Wpost1,
                                                     unsigned short* __restrict__ o) {
    __shared__ unsigned short sA[128][256];   // 64 KB
    const int tid = threadIdx.x;
    const int d = blockIdx.y;
    const int nb = blockIdx.x * 128;
    const float* Wp = (d == 0) ? Wpost0 : Wpost1;

    const int wid = tid >> 6, lane = tid & 63;
    const int wr = wid >> 1, wc = wid & 1;
    const int l15 = lane & 15, lk = lane >> 4;

    f32x4 acc[4][4];
    #pragma unroll
    for (int mf = 0; mf < 4; ++mf)
        #pragma unroll
        for (int cf = 0; cf < 4; ++cf) acc[mf][cf] = (f32x4){0.f, 0.f, 0.f, 0.f};

    #pragma unroll
    for (int pass = 0; pass < 2; ++pass) {
        __syncthreads();
        {
            const int n = tid >> 1, half = tid & 1;
            const float4* src = (const float4*)(Acat + (size_t)(nb + n) * 1024 + (d << 8)) + half * 32;
            #pragma unroll
            for (int j = 0; j < 32; j += 2) {
                const float4 v0 = src[j];
                const float4 v1 = src[j + 1];
                const int k0 = (half * 128 + j * 4) ^ ((n & 7) << 3);
                union { unsigned short s[8]; uint4 q; } pk;
                const float f0[8] = {v0.x, v0.y, v0.z, v0.w, v1.x, v1.y, v1.z, v1.w};
                #pragma unroll
                for (int q = 0; q < 8; ++q) {
                    const unsigned short hi = f2bf(f0[q]);
                    pk.s[q] = (pass == 0) ? hi : f2bf(f0[q] - bf2f(hi));
                }
                *(uint4*)&sA[n][k0] = pk.q;
            }
        }
        __syncthreads();

        #pragma unroll
        for (int ks = 0; ks < 8; ++ks) {
            const int ku = ks * 32 + lk * 8;
            short8_t a[4];
            #pragma unroll
            for (int mf = 0; mf < 4; ++mf) {
                const int row = wr * 64 + mf * 16 + l15;
                a[mf] = *(const short8_t*)&sA[row][ku ^ ((row & 7) << 3)];
            }
            short8_t bh[4], bl[4];
            #pragma unroll
            for (int cf = 0; cf < 4; ++cf) {
                const int col = wc * 64 + cf * 16 + l15;
                union { unsigned short s[8]; short8_t v; } h, l;
                #pragma unroll
                for (int q = 0; q < 8; ++q) {
                    const float f = Wp[(size_t)(ku + q) * 128 + col];
                    const unsigned short hi = f2bf(f);
                    h.s[q] = hi;
                    l.s[q] = f2bf(f - bf2f(hi));
                }
                bh[cf] = h.v; bl[cf] = l.v;
            }
            #pragma unroll
            for (int mf = 0; mf < 4; ++mf)
                #pragma unroll
                for (int cf = 0; cf < 4; ++cf) {
                    acc[mf][cf] = __builtin_amdgcn_mfma_f32_16x16x32_bf16(a[mf], bh[cf], acc[mf][cf], 0, 0, 0);
                    if (pass == 0)
                        acc[mf][cf] = __builtin_amdgcn_mfma_f32_16x16x32_bf16(a[mf], bl[cf], acc[mf][cf], 0, 0, 0);
                }
        }
    }

    const float inv_2c = 0.0625f;
    #pragma unroll
    for (int mf = 0; mf < 4; ++mf) {
        #pragma unroll
        for (int j = 0; j < 4; ++j) {
            const int n = nb + wr * 64 + mf * 16 + lk * 4 + j;
            #pragma unroll
            for (int cf = 0; cf < 4; ++cf) {
                const int col = wc * 64 + cf * 16 + l15;
                o[((size_t)n * 4 + d) * 128 + col] = f2bf(acc[mf][cf][j] * inv_2c);
            }
        }
    }
}

// ---------------- WaT: one-time transpose Wa(u,v,w) -> WaT[arr][v][w][u] bf16
__global__ __launch_bounds__(256) void watT_kernel(const float* __restrict__ Wa0,
                                                   const float* __restrict__ Wa1,
                                                   unsigned short* __restrict__ WaT) {
    __shared__ unsigned short tile[128][129];
    const int tid = threadIdx.x;
    const int v = blockIdx.x;
    const int arr = blockIdx.y;
    const float* Wa = (arr == 0) ? Wa0 : Wa1;
    {
        const int u = tid >> 1, half = tid & 1;
        const float4* src = (const float4*)(Wa + ((size_t)u * AA + v) * 128 + half * 64);
        #pragma unroll
        for (int j = 0; j < 16; ++j) {
            const float4 val = src[j];
            const int w = half * 64 + j * 4;
            tile[w + 0][u] = f2bf(val.x);
            tile[w + 1][u] = f2bf(val.y);
            tile[w + 2][u] = f2bf(val.z);
            tile[w + 3][u] = f2bf(val.w);
        }
    }
    __syncthreads();
    {
        const int w = tid >> 1, half = tid & 1;
        unsigned short* dst = WaT + (size_t)arr * 163840 + (size_t)v * 16384 + (size_t)w * 128;
        #pragma unroll
        for (int j = 0; j < 8; ++j) {
            const int u0 = half * 64 + j * 8;
            union { unsigned short s[8]; uint4 q; } pk;
            #pragma unroll
            for (int k = 0; k < 8; ++k) pk.s[k] = tile[w][u0 + k];
            *(uint4*)(dst + u0) = pk.q;
        }
    }
}

// ---------------- K5 (MFMA): out_d[n,w] = sum_v attr[n,v] * (o_d[n,:] @ Wa[:,v,:])
// o is already bf16 -> A-staging is a pure swizzled copy (no conversion).
__global__ __launch_bounds__(256) void attrm_kernel(const unsigned short* __restrict__ o,
                                                    const float* __restrict__ attr,
                                                    const unsigned short* __restrict__ WaT,
                                                    float* __restrict__ tmp) {
    __shared__ unsigned short sA[128][128];
    __shared__ unsigned short sB[128][128];
    __shared__ float sat[128][AA];
    const int tid = threadIdx.x;
    const int d = blockIdx.y;
    const int nb = blockIdx.x * 128;
    const unsigned short* Wp = WaT + (d == 0 ? 0 : 163840);

    {
        const int n = tid >> 1, half = tid & 1;
        const uint4* src = (const uint4*)(o + ((size_t)(nb + n) * 4 + d) * 128 + half * 64);
        #pragma unroll
        for (int j = 0; j < 8; ++j) {
            const int u0 = (half * 64 + j * 8) ^ ((n & 7) << 3);
            *(uint4*)&sA[n][u0] = src[j];
        }
    }
    for (int i = tid; i < 128 * AA; i += 256) ((float*)sat)[i] = attr[(size_t)nb * AA + i];

    const int wid = tid >> 6, lane = tid & 63;
    const int wr = wid >> 1, wc = wid & 1;
    const int lrow = lane & 15, lk = lane >> 4;

    f32x4 tot[4][4];
    #pragma unroll
    for (int mf = 0; mf < 4; ++mf)
        #pragma unroll
        for (int cf = 0; cf < 4; ++cf) tot[mf][cf] = (f32x4){0.f, 0.f, 0.f, 0.f};

    for (int v = 0; v < AA; ++v) {
        __syncthreads();
        {
            const uint4* src = (const uint4*)(Wp + (size_t)v * 16384);
            #pragma unroll
            for (int j = 0; j < 8; ++j) {
                const int cidx = tid + j * 256;
                const int w = cidx >> 4;
                const int u0 = ((cidx & 15) * 8) ^ ((w & 7) << 3);
                const uint4 val = src[cidx];
                *(uint4*)&sB[w][u0] = val;
            }
        }
        __syncthreads();

        f32x4 acc[4][4];
        #pragma unroll
        for (int mf = 0; mf < 4; ++mf)
            #pragma unroll
            for (int cf = 0; cf < 4; ++cf) acc[mf][cf] = (f32x4){0.f, 0.f, 0.f, 0.f};

        #pragma unroll
        for (int ks = 0; ks < 4; ++ks) {
            const int ku = ks * 32 + lk * 8;
            short8_t a[4], b[4];
            #pragma unroll
            for (int mf = 0; mf < 4; ++mf) {
                const int row = wr * 64 + mf * 16 + lrow;
                a[mf] = *(const short8_t*)&sA[row][ku ^ ((row & 7) << 3)];
            }
            #pragma unroll
            for (int cf = 0; cf < 4; ++cf) {
                const int col = wc * 64 + cf * 16 + lrow;
                b[cf] = *(const short8_t*)&sB[col][ku ^ ((col & 7) << 3)];
            }
            #pragma unroll
            for (int mf = 0; mf < 4; ++mf)
                #pragma unroll
                for (int cf = 0; cf < 4; ++cf)
                    acc[mf][cf] = __builtin_amdgcn_mfma_f32_16x16x32_bf16(a[mf], b[cf], acc[mf][cf], 0, 0, 0);
        }

        #pragma unroll
        for (int mf = 0; mf < 4; ++mf) {
            const int row0 = wr * 64 + mf * 16 + lk * 4;
            #pragma unroll
            for (int j = 0; j < 4; ++j) {
                const float wj = sat[row0 + j][v];
                #pragma unroll
                for (int cf = 0; cf < 4; ++cf)
                    tot[mf][cf][j] += wj * acc[mf][cf][j];
            }
        }
    }

    const float inv_ca = 0.027950849718747373f;
    #pragma unroll
    for (int mf = 0; mf < 4; ++mf) {
        #pragma unroll
        for (int j = 0; j < 4; ++j) {
            const int n = nb + wr * 64 + mf * 16 + lk * 4 + j;
            #pragma unroll
            for (int cf = 0; cf < 4; ++cf) {
                const int col = wc * 64 + cf * 16 + lrow;
                tmp[(size_t)d * 2048000 + (size_t)n * 128 + col] = tot[mf][cf][j] * inv_ca;
            }
        }
    }
}

// ---------------- pack: out[n][w][0..3] = {tmp_d planes} as float4
__global__ __launch_bounds__(256) void pack_kernel(const float* __restrict__ tmp,
                                                   float4* __restrict__ out4) {
    const size_t e = (size_t)blockIdx.x * 256 + threadIdx.x;
    out4[e] = make_float4(tmp[e], tmp[2048000 + e], tmp[4096000 + e], tmp[6144000 + e]);
}

extern "C" void kernel_launch(void* const* d_in, const int* in_sizes, int n_in,
                              void* d_out, int out_size, void* d_ws, size_t ws_size,
                              hipStream_t stream) {
    const float* nf    = (const float*)d_in[0];
    const float* attr  = (const float*)d_in[1];
    const float* sph   = (const float*)d_in[2];
    const float* rb    = (const float*)d_in[3];
    const int*   ei    = (const int*)d_in[4];
    const float* Wpre0 = (const float*)d_in[5];
    const float* Wpre1 = (const float*)d_in[6];
    const float* Wm1   = (const float*)d_in[7];
    const float* Wm2   = (const float*)d_in[8];
    const float* Wm3   = (const float*)d_in[9];
    const float* Wpost0= (const float*)d_in[10];
    const float* Wpost1= (const float*)d_in[11];
    const float* Wa0   = (const float*)d_in[12];
    const float* Wa1   = (const float*)d_in[13];
    float* out = (float*)d_out;

    float* ws = (float*)d_ws;
    // footprint identical to proven rounds: ends at Ys + 256000 float4
    ushort4* hb = (ushort4*)ws;                     // (N,128) ushort4 = 16 MB (first half of region 0)
    int* ipos = (int*)(ws + (size_t)4096000);      // 1 MB at byte 16,384,000; dead after mlp
    unsigned short* hmS = (unsigned short*)(ws + (size_t)8192000);
    float* Acat = ws + (size_t)16384000;
    int* perm = (int*)(Acat + (size_t)16384000);  // 256000 ints; dead after gather
    int* cur  = perm + 256000;                     // 16384
    int* cnt  = cur + 16384;                       // 16384
    int* ss   = cnt + 16384;                       // 256000
    int* rs   = ss + 256000;                       // 256000
    float4* Ys = (float4*)(rs + 256000);           // 256000 float4 -- END of footprint
    unsigned short* W3Thi = (unsigned short*)perm; // 64 KB, reuses dead perm
    unsigned short* W3Tlo = W3Thi + 32768;         // 64 KB, still inside perm's 1 MB
    unsigned short* o = (unsigned short*)ws;        // (N,4,128) bf16 = 16 MB, aliases hb (dead after wmsgm)
    float* tmp = Acat;                              // 4 x 2,048,000 f32
    unsigned short* WaT = (unsigned short*)(Acat + (size_t)8192000);

    hipMemsetAsync(Acat, 0, (size_t)NN * 1024 * sizeof(float), stream);
    hipMemsetAsync(cnt, 0, 16384 * sizeof(int), stream);

    pre_kernel<<<NN / 8, 256, 0, stream>>>(nf, Wpre0, Wpre1, hb);
    count_kernel<<<EE / 256, 256, 0, stream>>>(ei, cnt);
    scan_kernel<<<1, 1024, 0, stream>>>(cnt, cur);
    fill_kernel<<<EE / 256, 256, 0, stream>>>(ei, cur, perm, ipos);
    gather_kernel<<<EE / 256, 256, 0, stream>>>(perm, ei, (const float4*)sph, ss, rs, Ys);
    mlp_kernel<<<EE / 256, 256, 0, stream>>>(rb, Wm1, Wm2, ipos, hmS);
    w3t_kernel<<<128, 256, 0, stream>>>(Wm3, W3Thi, W3Tlo);   // overwrites perm (dead)
    wmsgm_kernel<<<EE / 64, 512, 0, stream>>>(hmS, W3Thi, W3Tlo, ss, rs, Ys, hb, Acat);
    postom_kernel<<<dim3(NN / 128, 4), 256, 0, stream>>>(Acat, Wpost0, Wpost1, o);
    watT_kernel<<<dim3(AA, 2), 256, 0, stream>>>(Wa0, Wa1, WaT);
    attrm_kernel<<<dim3(NN / 128, 4), 256, 0, stream>>>(o, attr, WaT, tmp);
    pack_kernel<<<8000, 256, 0, stream>>>(tmp, (float4*)out);
}